// Round 3
// baseline (346.303 us; speedup 1.0000x reference)
//
#include <hip/hip_runtime.h>
#include <hip/hip_bf16.h>

#define BB 4
#define SS 2048
#define EE 512
#define HH 8
#define DD 64

typedef __attribute__((ext_vector_type(8))) short bf16x8;   // 8 bf16 = 4 VGPRs
typedef __attribute__((ext_vector_type(4))) float f32x4;

__device__ __forceinline__ unsigned short f2bf(float f) {
    __hip_bfloat16 h = __float2bfloat16(f);   // round-to-nearest
    return *reinterpret_cast<unsigned short*>(&h);
}

// ---------------------------------------------------------------------------
// fp32 -> bf16 cast, 5 tensors in one launch (blockIdx.y selects).
// ---------------------------------------------------------------------------
__global__ __launch_bounds__(256)
void cast_all(const float* __restrict__ x,
              const float* __restrict__ wq, const float* __restrict__ wk,
              const float* __restrict__ wv, const float* __restrict__ wo,
              unsigned short* __restrict__ xb,
              unsigned short* __restrict__ wqb, unsigned short* __restrict__ wkb,
              unsigned short* __restrict__ wvb, unsigned short* __restrict__ wob)
{
    const int t = blockIdx.y;
    const float* src; unsigned short* dst; int n4;
    switch (t) {
        case 0: src = x;  dst = xb;  n4 = (BB*SS*EE)/4; break;
        case 1: src = wq; dst = wqb; n4 = (EE*EE)/4; break;
        case 2: src = wk; dst = wkb; n4 = (EE*EE)/4; break;
        case 3: src = wv; dst = wvb; n4 = (EE*EE)/4; break;
        default: src = wo; dst = wob; n4 = (EE*EE)/4; break;
    }
    const int i = blockIdx.x * 256 + threadIdx.x;
    if (i >= n4) return;
    const float4 v = reinterpret_cast<const float4*>(src)[i];
    ushort4 o;
    o.x = f2bf(v.x); o.y = f2bf(v.y); o.z = f2bf(v.z); o.w = f2bf(v.w);
    reinterpret_cast<ushort4*>(dst)[i] = o;
}

// ---------------------------------------------------------------------------
// MFMA GEMM: C[M,N] = bf16(A[M,K]) @ bf16(W[N,K])^T + bias[N]
// 128x128 tile, 4 waves (2x2 of 64x64), 16x16x32 bf16 MFMA, BK=32.
// Register double-buffer: next tile's global loads issued during MFMA phase.
// TRANSPOSE_V: when blockIdx.z==2, write C transposed per-head as
// Vt[b][h][d][s] (C/D layout makes 4 accum rows consecutive in s -> ushort4).
// ---------------------------------------------------------------------------
#define GPAD 40

template<typename OutT, bool TRANSPOSE_V>
__global__ __launch_bounds__(256)
void gemm_mfma_nt(const unsigned short* __restrict__ A,
                  const unsigned short* __restrict__ W0, const float* __restrict__ b0, OutT* __restrict__ C0,
                  const unsigned short* __restrict__ W1, const float* __restrict__ b1, OutT* __restrict__ C1,
                  const unsigned short* __restrict__ W2, const float* __restrict__ b2, OutT* __restrict__ C2,
                  int M, int N, int K)
{
    const unsigned short* W = (blockIdx.z == 0) ? W0 : (blockIdx.z == 1) ? W1 : W2;
    const float* bias       = (blockIdx.z == 0) ? b0 : (blockIdx.z == 1) ? b1 : b2;
    OutT* C                 = (blockIdx.z == 0) ? C0 : (blockIdx.z == 1) ? C1 : C2;

    __shared__ unsigned short As[128 * GPAD];
    __shared__ unsigned short Bs[128 * GPAD];

    const int tid  = threadIdx.x;
    const int wave = tid >> 6, lane = tid & 63;
    const int quad = lane >> 4, r16 = lane & 15;
    const int m0 = blockIdx.x * 128, n0 = blockIdx.y * 128;
    const int wm0 = (wave >> 1) * 64, wn0 = (wave & 1) * 64;

    const int srow = tid >> 2;          // 0..63 (+64 on second chunk)
    const int scol = (tid & 3) * 8;

    f32x4 acc[4][4];
    const f32x4 zero = {0.f, 0.f, 0.f, 0.f};
    #pragma unroll
    for (int i = 0; i < 4; ++i)
        #pragma unroll
        for (int j = 0; j < 4; ++j) acc[i][j] = zero;

    float4 areg[2], wreg[2];
    #pragma unroll
    for (int i = 0; i < 2; ++i) {
        areg[i] = *reinterpret_cast<const float4*>(&A[(size_t)(m0 + srow + 64 * i) * K + scol]);
        wreg[i] = *reinterpret_cast<const float4*>(&W[(size_t)(n0 + srow + 64 * i) * K + scol]);
    }

    for (int k0 = 0; k0 < K; k0 += 32) {
        __syncthreads();   // previous iteration's frag reads done
        #pragma unroll
        for (int i = 0; i < 2; ++i) {
            *reinterpret_cast<float4*>(&As[(srow + 64 * i) * GPAD + scol]) = areg[i];
            *reinterpret_cast<float4*>(&Bs[(srow + 64 * i) * GPAD + scol]) = wreg[i];
        }
        __syncthreads();
        if (k0 + 32 < K) {
            #pragma unroll
            for (int i = 0; i < 2; ++i) {
                areg[i] = *reinterpret_cast<const float4*>(&A[(size_t)(m0 + srow + 64 * i) * K + k0 + 32 + scol]);
                wreg[i] = *reinterpret_cast<const float4*>(&W[(size_t)(n0 + srow + 64 * i) * K + k0 + 32 + scol]);
            }
        }
        bf16x8 af[4], bfr[4];
        #pragma unroll
        for (int t = 0; t < 4; ++t) {
            af[t]  = *reinterpret_cast<bf16x8*>(&As[(wm0 + t * 16 + r16) * GPAD + quad * 8]);
            bfr[t] = *reinterpret_cast<bf16x8*>(&Bs[(wn0 + t * 16 + r16) * GPAD + quad * 8]);
        }
        #pragma unroll
        for (int mt = 0; mt < 4; ++mt)
            #pragma unroll
            for (int nt = 0; nt < 4; ++nt)
                acc[mt][nt] = __builtin_amdgcn_mfma_f32_16x16x32_bf16(
                    af[mt], bfr[nt], acc[mt][nt], 0, 0, 0);
    }

    // Epilogue. C/D layout: col = lane&15, row = quad*4 + reg (m89-verified).
    if (TRANSPOSE_V && blockIdx.z == 2) {
        // Vt[b][h][d][s]: flat = b*EE*SS + n*SS + s, s = m & (SS-1), b = m >> 11.
        #pragma unroll
        for (int mt = 0; mt < 4; ++mt) {
            const int m = m0 + wm0 + mt * 16 + quad * 4;   // 4 consecutive rows
            const int bb = m >> 11, s0 = m & (SS - 1);
            #pragma unroll
            for (int nt = 0; nt < 4; ++nt) {
                const int col = n0 + wn0 + nt * 16 + r16;
                const float bv = bias[col];
                ushort4 o;
                o.x = f2bf(acc[mt][nt][0] + bv);
                o.y = f2bf(acc[mt][nt][1] + bv);
                o.z = f2bf(acc[mt][nt][2] + bv);
                o.w = f2bf(acc[mt][nt][3] + bv);
                *reinterpret_cast<ushort4*>(
                    &((unsigned short*)C2)[(size_t)bb * EE * SS + (size_t)col * SS + s0]) = o;
            }
        }
        return;
    }
    #pragma unroll
    for (int mt = 0; mt < 4; ++mt) {
        #pragma unroll
        for (int nt = 0; nt < 4; ++nt) {
            const int col = n0 + wn0 + nt * 16 + r16;
            const float bv = bias[col];
            #pragma unroll
            for (int r = 0; r < 4; ++r) {
                const int row = m0 + wm0 + mt * 16 + quad * 4 + r;
                const float v = acc[mt][nt][r] + bv;
                if constexpr (sizeof(OutT) == 2)
                    C[(size_t)row * N + col] = (OutT)f2bf(v);
                else
                    C[(size_t)row * N + col] = (OutT)v;
            }
        }
    }
}

// ---------------------------------------------------------------------------
// MFMA flash attention. Block = 128 q-rows of one (head,batch); 4 waves, each
// owns 32 q-rows (2 m-tiles). V arrives pre-transposed [b][h][d][s] from the
// QKV GEMM -> no LDS transpose, no bank conflicts. Register prefetch of next
// K/Vt tile overlaps global latency with compute. exp2-domain softmax
// (log2e folded into entangle scale). All LDS rows padded to 68 shorts.
// ---------------------------------------------------------------------------
#define APAD 68

__global__ __launch_bounds__(256)
void attn_mfma(const unsigned short* __restrict__ Q,
               const unsigned short* __restrict__ K,
               const unsigned short* __restrict__ Vt,
               const float* __restrict__ ent,
               unsigned short* __restrict__ O)
{
    __shared__ unsigned short Qs[128 * APAD];    // [q][d]
    __shared__ unsigned short Ks[64 * APAD];     // [k][d]
    __shared__ unsigned short Vs[64 * APAD];     // [d][k]
    __shared__ unsigned short Ps[4][32 * APAD];  // per-wave [q32][k64]

    const int tid  = threadIdx.x;
    const int wave = tid >> 6, lane = tid & 63;
    const int quad = lane >> 4, r16 = lane & 15;
    const int q0 = blockIdx.x * 128;
    const int h  = blockIdx.y, b = blockIdx.z;
    const size_t base    = (size_t)b * SS * EE + (size_t)h * DD;       // Q/K/O rows
    const size_t base_vt = ((size_t)b * HH + h) * DD * SS;             // Vt rows

    const int srow = tid >> 3;          // 0..31 (+32 per chunk)
    const int scol = (tid & 7) * 8;

    // Stage Q tile: 128 rows x 64 bf16.
    #pragma unroll
    for (int i = 0; i < 4; ++i) {
        const int row = srow + 32 * i;
        *reinterpret_cast<float4*>(&Qs[row * APAD + scol]) =
            *reinterpret_cast<const float4*>(&Q[base + (size_t)(q0 + row) * EE + scol]);
    }

    // entangle * (1/8) * log2(e); softmax done in exp2 domain (base-invariant).
    float eq[2][4];
    #pragma unroll
    for (int mt = 0; mt < 2; ++mt)
        #pragma unroll
        for (int r = 0; r < 4; ++r)
            eq[mt][r] = ent[q0 + wave * 32 + mt * 16 + quad * 4 + r] * (0.125f * 1.44269504f);

    float m_i[2][4], l_i[2][4];
    f32x4 o_acc[2][4];
    const f32x4 zero = {0.f, 0.f, 0.f, 0.f};
    #pragma unroll
    for (int mt = 0; mt < 2; ++mt)
        #pragma unroll
        for (int r = 0; r < 4; ++r) {
            m_i[mt][r] = -1e30f; l_i[mt][r] = 0.f;
        }
    #pragma unroll
    for (int mt = 0; mt < 2; ++mt)
        #pragma unroll
        for (int dt = 0; dt < 4; ++dt) o_acc[mt][dt] = zero;

    float4 kreg[2], vreg[2];
    #pragma unroll
    for (int i = 0; i < 2; ++i) {
        const int row = srow + 32 * i;
        kreg[i] = *reinterpret_cast<const float4*>(&K[base + (size_t)row * EE + scol]);
        vreg[i] = *reinterpret_cast<const float4*>(&Vt[base_vt + (size_t)row * SS + scol]);
    }

    for (int kt = 0; kt < SS / 64; ++kt) {
        __syncthreads();   // all frag reads of previous tile complete
        #pragma unroll
        for (int i = 0; i < 2; ++i) {
            const int row = srow + 32 * i;
            *reinterpret_cast<float4*>(&Ks[row * APAD + scol]) = kreg[i];
            *reinterpret_cast<float4*>(&Vs[row * APAD + scol]) = vreg[i];
        }
        __syncthreads();
        if (kt + 1 < SS / 64) {
            const int kb = (kt + 1) * 64;
            #pragma unroll
            for (int i = 0; i < 2; ++i) {
                const int row = srow + 32 * i;
                kreg[i] = *reinterpret_cast<const float4*>(&K[base + (size_t)(kb + row) * EE + scol]);
                vreg[i] = *reinterpret_cast<const float4*>(&Vt[base_vt + (size_t)row * SS + kb + scol]);
            }
        }

        // QK^T: per m-tile a = Q[m=..+r16][d], b = K[n=..+r16][d].
        f32x4 s[2][4];
        #pragma unroll
        for (int mt = 0; mt < 2; ++mt)
            #pragma unroll
            for (int tn = 0; tn < 4; ++tn) s[mt][tn] = zero;
        #pragma unroll
        for (int mt = 0; mt < 2; ++mt) {
            const int qrow = (wave * 32 + mt * 16 + r16) * APAD;
            bf16x8 qf0 = *reinterpret_cast<bf16x8*>(&Qs[qrow + quad * 8]);
            bf16x8 qf1 = *reinterpret_cast<bf16x8*>(&Qs[qrow + 32 + quad * 8]);
            #pragma unroll
            for (int tn = 0; tn < 4; ++tn) {
                bf16x8 kf0 = *reinterpret_cast<bf16x8*>(&Ks[(tn * 16 + r16) * APAD + quad * 8]);
                bf16x8 kf1 = *reinterpret_cast<bf16x8*>(&Ks[(tn * 16 + r16) * APAD + 32 + quad * 8]);
                s[mt][tn] = __builtin_amdgcn_mfma_f32_16x16x32_bf16(qf0, kf0, s[mt][tn], 0, 0, 0);
                s[mt][tn] = __builtin_amdgcn_mfma_f32_16x16x32_bf16(qf1, kf1, s[mt][tn], 0, 0, 0);
            }
        }

        // Online softmax (exp2 domain). Row (mt, quad*4+r) spans 16 lanes.
        unsigned short* pw = &Ps[wave][0];
        #pragma unroll
        for (int mt = 0; mt < 2; ++mt) {
            #pragma unroll
            for (int r = 0; r < 4; ++r) {
                const float e = eq[mt][r];
                const float s0 = s[mt][0][r] * e, s1 = s[mt][1][r] * e;
                const float s2 = s[mt][2][r] * e, s3 = s[mt][3][r] * e;
                float mx = fmaxf(fmaxf(s0, s1), fmaxf(s2, s3));
                #pragma unroll
                for (int d = 1; d < 16; d <<= 1)
                    mx = fmaxf(mx, __shfl_xor(mx, d, 64));
                const float mn = fmaxf(m_i[mt][r], mx);
                const float alpha = exp2f(m_i[mt][r] - mn);
                m_i[mt][r] = mn;
                const float p0 = exp2f(s0 - mn), p1 = exp2f(s1 - mn);
                const float p2 = exp2f(s2 - mn), p3 = exp2f(s3 - mn);
                float ps = p0 + p1 + p2 + p3;
                #pragma unroll
                for (int d = 1; d < 16; d <<= 1)
                    ps += __shfl_xor(ps, d, 64);
                l_i[mt][r] = l_i[mt][r] * alpha + ps;
                #pragma unroll
                for (int dt = 0; dt < 4; ++dt) o_acc[mt][dt][r] *= alpha;
                const int prow = (mt * 16 + quad * 4 + r) * APAD;
                pw[prow +      r16] = f2bf(p0);
                pw[prow + 16 + r16] = f2bf(p1);
                pw[prow + 32 + r16] = f2bf(p2);
                pw[prow + 48 + r16] = f2bf(p3);
            }
        }
        // Per-wave LDS: in-wave waitcnt ordering suffices, no barrier.

        // PV: a = P[m=..+r16][k], b = Vs[n=d=..+r16][k].
        #pragma unroll
        for (int mt = 0; mt < 2; ++mt) {
            bf16x8 pf0 = *reinterpret_cast<bf16x8*>(&pw[(mt * 16 + r16) * APAD + quad * 8]);
            bf16x8 pf1 = *reinterpret_cast<bf16x8*>(&pw[(mt * 16 + r16) * APAD + 32 + quad * 8]);
            #pragma unroll
            for (int dt = 0; dt < 4; ++dt) {
                bf16x8 vf0 = *reinterpret_cast<bf16x8*>(&Vs[(dt * 16 + r16) * APAD + quad * 8]);
                bf16x8 vf1 = *reinterpret_cast<bf16x8*>(&Vs[(dt * 16 + r16) * APAD + 32 + quad * 8]);
                o_acc[mt][dt] = __builtin_amdgcn_mfma_f32_16x16x32_bf16(pf0, vf0, o_acc[mt][dt], 0, 0, 0);
                o_acc[mt][dt] = __builtin_amdgcn_mfma_f32_16x16x32_bf16(pf1, vf1, o_acc[mt][dt], 0, 0, 0);
            }
        }
    }

    // Epilogue: O[q][h*64+d] bf16, natural layout for the output projection.
    #pragma unroll
    for (int mt = 0; mt < 2; ++mt) {
        #pragma unroll
        for (int dt = 0; dt < 4; ++dt) {
            #pragma unroll
            for (int r = 0; r < 4; ++r) {
                const float v = o_acc[mt][dt][r] / l_i[mt][r];
                const int q = q0 + wave * 32 + mt * 16 + quad * 4 + r;
                O[base + (size_t)q * EE + dt * 16 + r16] = f2bf(v);
            }
        }
    }
}

extern "C" void kernel_launch(void* const* d_in, const int* in_sizes, int n_in,
                              void* d_out, int out_size, void* d_ws, size_t ws_size,
                              hipStream_t stream) {
    const float* x   = (const float*)d_in[0];
    const float* ent = (const float*)d_in[1];
    const float* Wq  = (const float*)d_in[2];
    const float* bq  = (const float*)d_in[3];
    const float* Wk  = (const float*)d_in[4];
    const float* bk  = (const float*)d_in[5];
    const float* Wv  = (const float*)d_in[6];
    const float* bv  = (const float*)d_in[7];
    const float* Wo  = (const float*)d_in[8];
    const float* bo  = (const float*)d_in[9];
    float* out = (float*)d_out;

    const size_t n_x = (size_t)BB * SS * EE;   // 4 Mi elements
    const size_t n_w = (size_t)EE * EE;

    unsigned short* xb  = (unsigned short*)d_ws;
    unsigned short* wqb = xb + n_x;
    unsigned short* wkb = wqb + n_w;
    unsigned short* wvb = wkb + n_w;
    unsigned short* wob = wvb + n_w;
    unsigned short* Qb  = wob + n_w;
    unsigned short* Kb  = Qb + n_x;
    unsigned short* Vtb = Kb + n_x;   // [b][h][d][s]
    unsigned short* AOb = Vtb + n_x;

    const int M = BB * SS;  // 8192

    dim3 gc(4096, 5, 1);
    cast_all<<<gc, 256, 0, stream>>>(x, Wq, Wk, Wv, Wo, xb, wqb, wkb, wvb, wob);

    dim3 gq(M / 128, EE / 128, 3);
    gemm_mfma_nt<unsigned short, true><<<gq, 256, 0, stream>>>(
        xb, wqb, bq, Qb, wkb, bk, Kb, wvb, bv, Vtb, M, EE, EE);

    dim3 ga(SS / 128, HH, BB);
    attn_mfma<<<ga, 256, 0, stream>>>(Qb, Kb, Vtb, ent, AOb);

    dim3 go(M / 128, EE / 128, 1);
    gemm_mfma_nt<float, false><<<go, 256, 0, stream>>>(
        AOb, wob, bo, out, wob, bo, out, wob, bo, out, M, EE, EE);
}